// Round 8
// baseline (373.295 us; speedup 1.0000x reference)
//
#include <hip/hip_runtime.h>
#include <stdint.h>

// R14: delete the last serial links (R13 = 153.7us kernel).
//   1. L1 via MFMA: W1+b1 packed as zero-padded K=32 fragment tile; px/py/pz
//      hi/lo-split across paired k-slots (error ~bf16^2, below epilogue
//      rounding). Replaces the 64-iter scalar chain + w1L staging.
//   2. Barrier 1 deleted: zv recomputed per-lane from t_rand (identical
//      expression in A-build and composite -> bit-identical); dist via
//      shfl_down; vdir per-thread in L4 epilogue. No setup phase.
//   3. Barrier 6 deleted: wave0 computes ALL rgb (16 MFMA) + composites;
//      same-wave LDS needs no barrier. Waves 1-3 exit after barrier 4,
//      freeing SIMD slots to the co-resident block early.
//   4. L3 B-prefetch extended to kq0-5 (A-frags are 16 regs, room exists).
// Barriers 6 -> 4. Tripwire: FETCH ~6MB / WRITE ~7MB (no spill), VGPR <=160.
// Predict kernel 153.7 -> ~135-142us. If <5us gain clean: structure floor.

#define NRAYS 4096

typedef unsigned short u16;
typedef __attribute__((ext_vector_type(8))) short short8;
typedef __attribute__((ext_vector_type(4))) float f32x4;

__device__ __forceinline__ u16 f2bf(float f) {
  union { float f; uint32_t i; } v; v.f = f;
  return (u16)((v.i + 0x7FFFu + ((v.i >> 16) & 1u)) >> 16);
}
__device__ __forceinline__ float bf2f(u16 u) {
  union { uint32_t i; float f; } v; v.i = ((uint32_t)u) << 16; return v.f;
}
// packed fp32->bf16 (RNE), lo -> bits 15:0, hi -> bits 31:16 (bit-identical to f2bf)
__device__ __forceinline__ uint32_t cvtpk(float lo, float hi) {
  uint32_t r;
  asm("v_cvt_pk_bf16_f32 %0, %1, %2" : "=v"(r) : "v"(lo), "v"(hi));
  return r;
}

// stratified z sample for slot j (MUST stay textually identical everywhere)
__device__ __forceinline__ float zval(int j, float tr) {
  float fj = (float)j;
  float zj = 0.5f + 2.0f * (fj / 63.0f);
  float lower = (j == 0)  ? zj : 0.5f * (zj + (0.5f + 2.0f * ((fj - 1.0f) / 63.0f)));
  float upper = (j == 63) ? zj : 0.5f * (zj + (0.5f + 2.0f * ((fj + 1.0f) / 63.0f)));
  return lower + (upper - lower) * tr;
}

// fragment-contiguous index for a [N][K=256] tile (8 kq blocks)
__device__ __forceinline__ int fragidx(int n, int k) {
  return ((((n >> 4) * 8 + (k >> 5)) * 64 + ((k >> 3) & 3) * 16 + (n & 15)) << 3) + (k & 7);
}
// same for a [N][K=32] tile (1 kq block)
__device__ __forceinline__ int fragidx32(int n, int k) {
  return (((n >> 4) * 64 + ((k >> 3) & 3) * 16 + (n & 15)) << 3) + (k & 7);
}

// ---------------- weight pack (fp32 -> bf16 fragment tiles) ----------------
// ws (bf16 elems): W2f @0 (65536), W3f @65536 (65536), W4f @131072 (32768),
//   Wd-pad @163840 (4096: [256K][16N] col0=Wd), W5-pad @167936 (2048),
//   W1-pad @169984 (8192: [256N][32K], k0/1=W1r0, k2/3=W1r1, k4/5=W1r2, k6=b1)
__global__ void pack_weights(const float* __restrict__ W1, const float* __restrict__ b1,
                             const float* __restrict__ W2, const float* __restrict__ W3,
                             const float* __restrict__ W4, const float* __restrict__ Wd,
                             const float* __restrict__ W5, u16* __restrict__ ws) {
  int idx = blockIdx.x * 256 + threadIdx.x;   // grid covers exactly 178176
  float v;
  int dst;
  if (idx < 65536) {
    int k = idx >> 8, n = idx & 255;          // W2 row-major [k][n]
    v = W2[idx];
    dst = fragidx(n, k);
  } else if (idx < 131072) {
    int o = idx - 65536, k = o >> 8, n = o & 255;
    v = W3[o];
    dst = 65536 + fragidx(n, k);
  } else if (idx < 163840) {
    int o = idx - 131072, k = o >> 7, n = o & 127;  // W4 row-major [k][128]
    v = W4[o];
    dst = 131072 + fragidx(n, k);
  } else if (idx < 167936) {
    int o = idx - 163840, k = o >> 4, n = o & 15;   // Wd [256][1] padded to 16 cols
    v = (n == 0) ? Wd[k] : 0.f;
    dst = 163840 + fragidx(n, k);
  } else if (idx < 169984) {
    int o = idx - 167936, k = o >> 4, n = o & 15;   // W5 [128][3] padded to 16 cols
    v = (n < 3) ? W5[k * 3 + n] : 0.f;
    dst = 167936 + fragidx(n, k);
  } else {
    int o = idx - 169984, k = o >> 8, n = o & 255;  // W1-pad [256N][32K]
    if (k < 6)      v = W1[(k >> 1) * 256 + n];     // k0/1: row0; k2/3: row1; k4/5: row2
    else if (k == 6) v = b1[n];
    else            v = 0.f;
    dst = 169984 + fragidx32(n, k);
  }
  ws[dst] = f2bf(v);
}

#define MFMA __builtin_amdgcn_mfma_f32_16x16x32_bf16
#define ZER4 (f32x4){0.f, 0.f, 0.f, 0.f}

// declare + load the 4 A row-tile fragments for k-slice SQ from ACT
#define LDA4(ACT, SQ)                                                          \
    short8 av0 = *(const short8*)((ACT) + m0 * 256 + (((SQ) ^ (m0 & 31)) << 3)); \
    short8 av1 = *(const short8*)((ACT) + m1 * 256 + (((SQ) ^ (m1 & 31)) << 3)); \
    short8 av2 = *(const short8*)((ACT) + m2 * 256 + (((SQ) ^ (m2 & 31)) << 3)); \
    short8 av3 = *(const short8*)((ACT) + m3 * 256 + (((SQ) ^ (m3 & 31)) << 3))

// 16 MFMA: 4 row-tiles (av0..av3) x 4 B col-tiles (args)
#define MF16v(B0, B1, B2_, B3_) do {                                         \
    c00 = MFMA(av0, B0, c00, 0, 0, 0); c10 = MFMA(av1, B0, c10, 0, 0, 0);    \
    c20 = MFMA(av2, B0, c20, 0, 0, 0); c30 = MFMA(av3, B0, c30, 0, 0, 0);    \
    c01 = MFMA(av0, B1, c01, 0, 0, 0); c11 = MFMA(av1, B1, c11, 0, 0, 0);    \
    c21 = MFMA(av2, B1, c21, 0, 0, 0); c31 = MFMA(av3, B1, c31, 0, 0, 0);    \
    c02 = MFMA(av0, B2_, c02, 0, 0, 0); c12 = MFMA(av1, B2_, c12, 0, 0, 0);  \
    c22 = MFMA(av2, B2_, c22, 0, 0, 0); c32 = MFMA(av3, B2_, c32, 0, 0, 0);  \
    c03 = MFMA(av0, B3_, c03, 0, 0, 0); c13 = MFMA(av1, B3_, c13, 0, 0, 0);  \
    c23 = MFMA(av2, B3_, c23, 0, 0, 0); c33 = MFMA(av3, B3_, c33, 0, 0, 0);  \
  } while (0)

// store one 16x16 C-tile (f32x4 CV), row-tile mt, column ng, into swizzled ACT
#define EPIC(CV, mt, ng, addv, ACT) do {                                     \
    int su_ = ((ng) >> 3), so_ = ((ng) & 7);                                 \
    float f0_ = fmaxf((CV)[0] + (addv), 0.f);                                \
    float f1_ = fmaxf((CV)[1] + (addv), 0.f);                                \
    float f2_ = fmaxf((CV)[2] + (addv), 0.f);                                \
    float f3_ = fmaxf((CV)[3] + (addv), 0.f);                                \
    uint32_t p01_ = cvtpk(f0_, f1_), p23_ = cvtpk(f2_, f3_);                 \
    int mmb_ = (mt) * 16 + quad * 4;                                         \
    (ACT)[(mmb_ + 0) * 256 + ((su_ ^ ((mmb_ + 0) & 31)) << 3) + so_] = (u16)p01_;         \
    (ACT)[(mmb_ + 1) * 256 + ((su_ ^ ((mmb_ + 1) & 31)) << 3) + so_] = (u16)(p01_ >> 16); \
    (ACT)[(mmb_ + 2) * 256 + ((su_ ^ ((mmb_ + 2) & 31)) << 3) + so_] = (u16)p23_;         \
    (ACT)[(mmb_ + 3) * 256 + ((su_ ^ ((mmb_ + 3) & 31)) << 3) + so_] = (u16)(p23_ >> 16); \
  } while (0)

__global__ void __launch_bounds__(256, 2) nerf_fused(
    const float* __restrict__ rays_o, const float* __restrict__ rays_d,
    const float* __restrict__ t_rand,
    const float* __restrict__ b2, const float* __restrict__ b3,
    const float* __restrict__ bd,
    const float* __restrict__ W4, const float* __restrict__ b4,
    const float* __restrict__ b5,
    const u16* __restrict__ wpack, float* __restrict__ out) {
  __shared__ u16   actA[64 * 256];   // 32 KB, XOR-swizzled slots (ping)
  __shared__ u16   actB[64 * 256];   // 32 KB (pong)
  __shared__ float dens[64];
  __shared__ float rgbL[64 * 4];

  const int t = threadIdx.x;
  const int lane = t & 63;
  const int wv = t >> 6;        // 0..3
  const int quad = lane >> 4;
  const int l15 = lane & 15;
  const int ray = blockIdx.x;
  const int m0 = l15, m1 = l15 + 16, m2 = l15 + 32, m3 = l15 + 48;

  // ---- prefetch W1 frag (16 regs) + B2 kq0-3 (64 regs) ----
  short8 W1f0, W1f1, W1f2, W1f3;
  {
    const u16* w1b = wpack + 169984 + (wv * 4) * 512 + lane * 8;
    W1f0 = *(const short8*)(w1b);
    W1f1 = *(const short8*)(w1b + 512);
    W1f2 = *(const short8*)(w1b + 1024);
    W1f3 = *(const short8*)(w1b + 1536);
  }
  short8 B2a[8], B2b[8], B2c[8], B2d[8];
  const u16* q0 = wpack + (wv * 4 + 0) * 4096 + lane * 8;
  const u16* q1 = wpack + (wv * 4 + 1) * 4096 + lane * 8;
  const u16* q2 = wpack + (wv * 4 + 2) * 4096 + lane * 8;
  const u16* q3 = wpack + (wv * 4 + 3) * 4096 + lane * 8;
#pragma unroll
  for (int kq = 0; kq < 4; kq++) {
    B2a[kq] = *(const short8*)(q0 + kq * 512);
    B2b[kq] = *(const short8*)(q1 + kq * 512);
    B2c[kq] = *(const short8*)(q2 + kq * 512);
    B2d[kq] = *(const short8*)(q3 + kq * 512);
  }

  const float rox = rays_o[ray * 3 + 0], roy = rays_o[ray * 3 + 1], roz = rays_o[ray * 3 + 2];
  const float rdx = rays_d[ray * 3 + 0], rdy = rays_d[ray * 3 + 1], rdz = rays_d[ray * 3 + 2];

  // ---- layer 1 via MFMA: A built in regs (hi/lo split), no barrier before ----
  {
    short8 avz = {0, 0, 0, 0, 0, 0, 0, 0};
    short8 av0 = avz, av1 = avz, av2 = avz, av3 = avz;
    if (quad == 0) {
#pragma unroll
      for (int r = 0; r < 4; r++) {
        int m = l15 + r * 16;
        float tr = t_rand[ray * 64 + m];
        float zm = zval(m, tr);
        float px = rox + rdx * zm, py = roy + rdy * zm, pz = roz + rdz * zm;
        u16 xh = f2bf(px); float xl = px - bf2f(xh);
        u16 yh = f2bf(py); float yl = py - bf2f(yh);
        u16 zh = f2bf(pz); float zl = pz - bf2f(zh);
        short8 f;
        f[0] = (short)xh; f[1] = (short)f2bf(xl);
        f[2] = (short)yh; f[3] = (short)f2bf(yl);
        f[4] = (short)zh; f[5] = (short)f2bf(zl);
        f[6] = (short)0x3F80; f[7] = 0;
        if (r == 0) av0 = f; else if (r == 1) av1 = f;
        else if (r == 2) av2 = f; else av3 = f;
      }
    }
    f32x4 c00 = ZER4, c01 = ZER4, c02 = ZER4, c03 = ZER4;
    f32x4 c10 = ZER4, c11 = ZER4, c12 = ZER4, c13 = ZER4;
    f32x4 c20 = ZER4, c21 = ZER4, c22 = ZER4, c23 = ZER4;
    f32x4 c30 = ZER4, c31 = ZER4, c32 = ZER4, c33 = ZER4;
    MF16v(W1f0, W1f1, W1f2, W1f3);
    // fetch B2 kq4-7 (overlaps EPIC + barrier)
#pragma unroll
    for (int kq = 4; kq < 8; kq++) {
      B2a[kq] = *(const short8*)(q0 + kq * 512);
      B2b[kq] = *(const short8*)(q1 + kq * 512);
      B2c[kq] = *(const short8*)(q2 + kq * 512);
      B2d[kq] = *(const short8*)(q3 + kq * 512);
    }
    int ng0 = wv * 64 + l15;
    EPIC(c00, 0, ng0, 0.f, actA); EPIC(c10, 1, ng0, 0.f, actA);
    EPIC(c20, 2, ng0, 0.f, actA); EPIC(c30, 3, ng0, 0.f, actA);
    EPIC(c01, 0, ng0 + 16, 0.f, actA); EPIC(c11, 1, ng0 + 16, 0.f, actA);
    EPIC(c21, 2, ng0 + 16, 0.f, actA); EPIC(c31, 3, ng0 + 16, 0.f, actA);
    EPIC(c02, 0, ng0 + 32, 0.f, actA); EPIC(c12, 1, ng0 + 32, 0.f, actA);
    EPIC(c22, 2, ng0 + 32, 0.f, actA); EPIC(c32, 3, ng0 + 32, 0.f, actA);
    EPIC(c03, 0, ng0 + 48, 0.f, actA); EPIC(c13, 1, ng0 + 48, 0.f, actA);
    EPIC(c23, 2, ng0 + 48, 0.f, actA); EPIC(c33, 3, ng0 + 48, 0.f, actA);
  }
  __syncthreads();                                          // barrier 1 (of 4)

  short8 B3a[6], B3b[6], B3c[6], B3d[6];     // L3 kq0-5 prefetch (filled in L2)

  // ---- layer 2: h2 = relu(h1@W2 + b2) : reads actA, writes actB ----
  {
    int ng0 = wv * 64 + l15;
    float bi0 = b2[ng0], bi1 = b2[ng0 + 16], bi2 = b2[ng0 + 32], bi3 = b2[ng0 + 48];
    f32x4 c00 = ZER4, c01 = ZER4, c02 = ZER4, c03 = ZER4;
    f32x4 c10 = ZER4, c11 = ZER4, c12 = ZER4, c13 = ZER4;
    f32x4 c20 = ZER4, c21 = ZER4, c22 = ZER4, c23 = ZER4;
    f32x4 c30 = ZER4, c31 = ZER4, c32 = ZER4, c33 = ZER4;
#pragma unroll
    for (int kq = 0; kq < 8; kq++) {
      LDA4(actA, kq * 4 + quad);
      MF16v(B2a[kq], B2b[kq], B2c[kq], B2d[kq]);
    }
    // prefetch L3 B kq0-5
    {
      const u16* r0 = wpack + 65536 + (wv * 4 + 0) * 4096 + lane * 8;
      const u16* r1 = wpack + 65536 + (wv * 4 + 1) * 4096 + lane * 8;
      const u16* r2 = wpack + 65536 + (wv * 4 + 2) * 4096 + lane * 8;
      const u16* r3 = wpack + 65536 + (wv * 4 + 3) * 4096 + lane * 8;
#pragma unroll
      for (int kq = 0; kq < 6; kq++) {
        B3a[kq] = *(const short8*)(r0 + kq * 512);
        B3b[kq] = *(const short8*)(r1 + kq * 512);
        B3c[kq] = *(const short8*)(r2 + kq * 512);
        B3d[kq] = *(const short8*)(r3 + kq * 512);
      }
    }
    EPIC(c00, 0, ng0, bi0, actB); EPIC(c10, 1, ng0, bi0, actB);
    EPIC(c20, 2, ng0, bi0, actB); EPIC(c30, 3, ng0, bi0, actB);
    EPIC(c01, 0, ng0 + 16, bi1, actB); EPIC(c11, 1, ng0 + 16, bi1, actB);
    EPIC(c21, 2, ng0 + 16, bi1, actB); EPIC(c31, 3, ng0 + 16, bi1, actB);
    EPIC(c02, 0, ng0 + 32, bi2, actB); EPIC(c12, 1, ng0 + 32, bi2, actB);
    EPIC(c22, 2, ng0 + 32, bi2, actB); EPIC(c32, 3, ng0 + 32, bi2, actB);
    EPIC(c03, 0, ng0 + 48, bi3, actB); EPIC(c13, 1, ng0 + 48, bi3, actB);
    EPIC(c23, 2, ng0 + 48, bi3, actB); EPIC(c33, 3, ng0 + 48, bi3, actB);
  }
  __syncthreads();                                          // barrier 2

  short8 L4a[2], L4b[2], L4d[2];             // L4 kq0-1 prefetch (filled in L3)

  // ---- layer 3: h3 = relu(h2@W3 + b3) : reads actB, writes actA ----
  {
    int ng0 = wv * 64 + l15;
    float bi0 = b3[ng0], bi1 = b3[ng0 + 16], bi2 = b3[ng0 + 32], bi3 = b3[ng0 + 48];
    const u16* r0 = wpack + 65536 + (wv * 4 + 0) * 4096 + lane * 8;
    const u16* r1 = wpack + 65536 + (wv * 4 + 1) * 4096 + lane * 8;
    const u16* r2 = wpack + 65536 + (wv * 4 + 2) * 4096 + lane * 8;
    const u16* r3 = wpack + 65536 + (wv * 4 + 3) * 4096 + lane * 8;
    f32x4 c00 = ZER4, c01 = ZER4, c02 = ZER4, c03 = ZER4;
    f32x4 c10 = ZER4, c11 = ZER4, c12 = ZER4, c13 = ZER4;
    f32x4 c20 = ZER4, c21 = ZER4, c22 = ZER4, c23 = ZER4;
    f32x4 c30 = ZER4, c31 = ZER4, c32 = ZER4, c33 = ZER4;
#pragma unroll
    for (int kq = 0; kq < 8; kq++) {
      short8 b0, b1v, b2v, b3v;
      if (kq < 6) { b0 = B3a[kq]; b1v = B3b[kq]; b2v = B3c[kq]; b3v = B3d[kq]; }
      else {
        b0 = *(const short8*)(r0 + kq * 512);
        b1v = *(const short8*)(r1 + kq * 512);
        b2v = *(const short8*)(r2 + kq * 512);
        b3v = *(const short8*)(r3 + kq * 512);
      }
      LDA4(actB, kq * 4 + quad);
      MF16v(b0, b1v, b2v, b3v);
    }
    // prefetch L4 B kq0-1 + density-frag kq0-1
    {
      const u16* s0 = wpack + 131072 + (wv * 2 + 0) * 4096 + lane * 8;
      const u16* s1 = wpack + 131072 + (wv * 2 + 1) * 4096 + lane * 8;
      const u16* sD = wpack + 163840 + lane * 8;
#pragma unroll
      for (int kq = 0; kq < 2; kq++) {
        L4a[kq] = *(const short8*)(s0 + kq * 512);
        L4b[kq] = *(const short8*)(s1 + kq * 512);
        L4d[kq] = *(const short8*)(sD + kq * 512);
      }
    }
    EPIC(c00, 0, ng0, bi0, actA); EPIC(c10, 1, ng0, bi0, actA);
    EPIC(c20, 2, ng0, bi0, actA); EPIC(c30, 3, ng0, bi0, actA);
    EPIC(c01, 0, ng0 + 16, bi1, actA); EPIC(c11, 1, ng0 + 16, bi1, actA);
    EPIC(c21, 2, ng0 + 16, bi1, actA); EPIC(c31, 3, ng0 + 16, bi1, actA);
    EPIC(c02, 0, ng0 + 32, bi2, actA); EPIC(c12, 1, ng0 + 32, bi2, actA);
    EPIC(c22, 2, ng0 + 32, bi2, actA); EPIC(c32, 3, ng0 + 32, bi2, actA);
    EPIC(c03, 0, ng0 + 48, bi3, actA); EPIC(c13, 1, ng0 + 48, bi3, actA);
    EPIC(c23, 2, ng0 + 48, bi3, actA); EPIC(c33, 3, ng0 + 48, bi3, actA);
  }
  __syncthreads();                                          // barrier 3

  short8 W5f[4];                             // rgb B-frag prefetch (wave0 only)

  // ---- layer 4: h4 = relu(h3@W4 + vdir-term + b4), N=128; + fused density ----
  {
    float nrm = sqrtf(rdx * rdx + rdy * rdy + rdz * rdz) + 1e-8f;
    float v0 = rdx / nrm, v1 = rdy / nrm, v2 = rdz / nrm;
    int ng0 = wv * 32 + l15;
    int ng1 = ng0 + 16;
    float ad0 = b4[ng0] + v0 * W4[32768 + ng0] + v1 * W4[32896 + ng0] + v2 * W4[33024 + ng0];
    float ad1 = b4[ng1] + v0 * W4[32768 + ng1] + v1 * W4[32896 + ng1] + v2 * W4[33024 + ng1];
    const u16* s0 = wpack + 131072 + (wv * 2 + 0) * 4096 + lane * 8;
    const u16* s1 = wpack + 131072 + (wv * 2 + 1) * 4096 + lane * 8;
    const u16* sD = wpack + 163840 + lane * 8;
    f32x4 c00 = ZER4, c01 = ZER4;
    f32x4 c10 = ZER4, c11 = ZER4;
    f32x4 c20 = ZER4, c21 = ZER4;
    f32x4 c30 = ZER4, c31 = ZER4;
    f32x4 c40 = ZER4, c41 = ZER4, c42 = ZER4, c43 = ZER4;   // density
#pragma unroll
    for (int kq = 0; kq < 8; kq++) {
      short8 b0 = (kq < 2) ? L4a[kq] : *(const short8*)(s0 + kq * 512);
      short8 b1v = (kq < 2) ? L4b[kq] : *(const short8*)(s1 + kq * 512);
      short8 bD = (kq < 2) ? L4d[kq] : *(const short8*)(sD + kq * 512);
      LDA4(actA, kq * 4 + quad);
      c00 = MFMA(av0, b0, c00, 0, 0, 0); c10 = MFMA(av1, b0, c10, 0, 0, 0);
      c20 = MFMA(av2, b0, c20, 0, 0, 0); c30 = MFMA(av3, b0, c30, 0, 0, 0);
      c01 = MFMA(av0, b1v, c01, 0, 0, 0); c11 = MFMA(av1, b1v, c11, 0, 0, 0);
      c21 = MFMA(av2, b1v, c21, 0, 0, 0); c31 = MFMA(av3, b1v, c31, 0, 0, 0);
      c40 = MFMA(av0, bD, c40, 0, 0, 0); c41 = MFMA(av1, bD, c41, 0, 0, 0);
      c42 = MFMA(av2, bD, c42, 0, 0, 0); c43 = MFMA(av3, bD, c43, 0, 0, 0);
    }
    if (wv == 0) {       // only wave 0 needs W5 (it computes all rgb)
      const u16* s5 = wpack + 167936 + lane * 8;
#pragma unroll
      for (int kq = 0; kq < 4; kq++) W5f[kq] = *(const short8*)(s5 + kq * 512);
    }
    EPIC(c00, 0, ng0, ad0, actB); EPIC(c10, 1, ng0, ad0, actB);
    EPIC(c20, 2, ng0, ad0, actB); EPIC(c30, 3, ng0, ad0, actB);
    EPIC(c01, 0, ng1, ad1, actB); EPIC(c11, 1, ng1, ad1, actB);
    EPIC(c21, 2, ng1, ad1, actB); EPIC(c31, 3, ng1, ad1, actB);
    if (wv == 0 && l15 == 0) {
#pragma unroll
      for (int r = 0; r < 4; r++) {
        dens[ 0 + quad * 4 + r] = c40[r];
        dens[16 + quad * 4 + r] = c41[r];
        dens[32 + quad * 4 + r] = c42[r];
        dens[48 + quad * 4 + r] = c43[r];
      }
    }
  }
  __syncthreads();                                          // barrier 4 (last)

  // ---- wave 0: rgb (all rows via MFMA) + compositing; waves 1-3 exit ----
  if (wv == 0) {
    {
      f32x4 cR0 = ZER4, cR1 = ZER4, cR2 = ZER4, cR3 = ZER4;
#pragma unroll
      for (int kq = 0; kq < 4; kq++) {
        LDA4(actB, kq * 4 + quad);
        cR0 = MFMA(av0, W5f[kq], cR0, 0, 0, 0);
        cR1 = MFMA(av1, W5f[kq], cR1, 0, 0, 0);
        cR2 = MFMA(av2, W5f[kq], cR2, 0, 0, 0);
        cR3 = MFMA(av3, W5f[kq], cR3, 0, 0, 0);
      }
      if (l15 < 3) {
        float b5v = b5[l15];
#pragma unroll
        for (int r = 0; r < 4; r++) {
          rgbL[( 0 + quad * 4 + r) * 4 + l15] = 1.f / (1.f + __expf(-(cR0[r] + b5v)));
          rgbL[(16 + quad * 4 + r) * 4 + l15] = 1.f / (1.f + __expf(-(cR1[r] + b5v)));
          rgbL[(32 + quad * 4 + r) * 4 + l15] = 1.f / (1.f + __expf(-(cR2[r] + b5v)));
          rgbL[(48 + quad * 4 + r) * 4 + l15] = 1.f / (1.f + __expf(-(cR3[r] + b5v)));
        }
      }
    }
    // compositing (zv recomputed per lane, identical expression -> bit-identical)
    {
      int j = lane;
      float tr = t_rand[ray * 64 + j];
      float zvj = zval(j, tr);
      float zvn = __shfl_down(zvj, 1);
      float dist = (j < 63) ? (zvn - zvj) : 1e10f;
      float bd0 = bd[0];
      float alpha = 1.f - __expf(-fmaxf(dens[j] + bd0, 0.f) * dist);
      float v = 1.f - alpha + 1e-10f;
      float pscan = v;
#pragma unroll
      for (int d = 1; d < 64; d <<= 1) {
        float o = __shfl_up(pscan, d);
        if (j >= d) pscan *= o;
      }
      float T = __shfl_up(pscan, 1);
      if (j == 0) T = 1.f;
      float w = alpha * T;
      float r0 = w * rgbL[j * 4 + 0];
      float r1 = w * rgbL[j * 4 + 1];
      float r2 = w * rgbL[j * 4 + 2];
      float dp = w * zvj;
      float ac = w;
#pragma unroll
      for (int d = 32; d; d >>= 1) {
        r0 += __shfl_down(r0, d);
        r1 += __shfl_down(r1, d);
        r2 += __shfl_down(r2, d);
        dp += __shfl_down(dp, d);
        ac += __shfl_down(ac, d);
      }
      if (j == 0) {
        float bg = 1.f - ac;
        out[ray * 3 + 0] = r0 + bg;
        out[ray * 3 + 1] = r1 + bg;
        out[ray * 3 + 2] = r2 + bg;
        out[NRAYS * 3 + ray] = dp;
        out[NRAYS * 4 + ray] = ac;
      }
    }
  }
}

extern "C" void kernel_launch(void* const* d_in, const int* in_sizes, int n_in,
                              void* d_out, int out_size, void* d_ws, size_t ws_size,
                              hipStream_t stream) {
  const float* rays_o = (const float*)d_in[0];
  const float* rays_d = (const float*)d_in[1];
  const float* t_rand = (const float*)d_in[2];
  const float* W1 = (const float*)d_in[3];
  const float* b1 = (const float*)d_in[4];
  const float* W2 = (const float*)d_in[5];
  const float* b2 = (const float*)d_in[6];
  const float* W3 = (const float*)d_in[7];
  const float* b3 = (const float*)d_in[8];
  const float* Wd = (const float*)d_in[9];
  const float* bd = (const float*)d_in[10];
  const float* W4 = (const float*)d_in[11];
  const float* b4 = (const float*)d_in[12];
  const float* W5 = (const float*)d_in[13];
  const float* b5 = (const float*)d_in[14];
  u16* wpack = (u16*)d_ws;
  float* out = (float*)d_out;

  pack_weights<<<696, 256, 0, stream>>>(W1, b1, W2, W3, W4, Wd, W5, wpack);
  nerf_fused<<<NRAYS, 256, 0, stream>>>(rays_o, rays_d, t_rand, b2, b3,
                                        bd, W4, b4, b5, wpack, out);
}

// Round 9
// 232.719 us; speedup vs baseline: 1.6041x; 1.6041x over previous
//
#include <hip/hip_runtime.h>
#include <stdint.h>

// R15: R14's structure (L1-via-MFMA, 4 barriers, wave0 tail, bank-conflict 0)
// with R13's register discipline restored. R14 post-mortem: spill came from
// (a) B2 kq4-7 fetched while L1 acc(64)+B2[4](64)+W1f(16) live ~230, and
// (b) L3 prefetch 6-deep (96) against acc(64)+A(16)+L4 prefetch ~240.
// Empirical ceiling: live-set ~210 fits (R13's L2 loop), ~230+ spills.
// Changes vs R14:
//   1. B2 kq4-7 issued AFTER L1's EPIC (acc dead) -> L1 peak ~150.
//   2. L3 prefetch back to 4-deep (kq0-3) -> L3 peak ~150.
// Tripwire: FETCH ~6MB / WRITE ~7MB, VGPR 128. Predict 153.7 -> ~135-145us.
// If clean but >=150: deletions were latency-hidden -> structure floor.

#define NRAYS 4096

typedef unsigned short u16;
typedef __attribute__((ext_vector_type(8))) short short8;
typedef __attribute__((ext_vector_type(4))) float f32x4;

__device__ __forceinline__ u16 f2bf(float f) {
  union { float f; uint32_t i; } v; v.f = f;
  return (u16)((v.i + 0x7FFFu + ((v.i >> 16) & 1u)) >> 16);
}
__device__ __forceinline__ float bf2f(u16 u) {
  union { uint32_t i; float f; } v; v.i = ((uint32_t)u) << 16; return v.f;
}
// packed fp32->bf16 (RNE), lo -> bits 15:0, hi -> bits 31:16 (bit-identical to f2bf)
__device__ __forceinline__ uint32_t cvtpk(float lo, float hi) {
  uint32_t r;
  asm("v_cvt_pk_bf16_f32 %0, %1, %2" : "=v"(r) : "v"(lo), "v"(hi));
  return r;
}

// stratified z sample for slot j (MUST stay textually identical everywhere)
__device__ __forceinline__ float zval(int j, float tr) {
  float fj = (float)j;
  float zj = 0.5f + 2.0f * (fj / 63.0f);
  float lower = (j == 0)  ? zj : 0.5f * (zj + (0.5f + 2.0f * ((fj - 1.0f) / 63.0f)));
  float upper = (j == 63) ? zj : 0.5f * (zj + (0.5f + 2.0f * ((fj + 1.0f) / 63.0f)));
  return lower + (upper - lower) * tr;
}

// fragment-contiguous index for a [N][K=256] tile (8 kq blocks)
__device__ __forceinline__ int fragidx(int n, int k) {
  return ((((n >> 4) * 8 + (k >> 5)) * 64 + ((k >> 3) & 3) * 16 + (n & 15)) << 3) + (k & 7);
}
// same for a [N][K=32] tile (1 kq block)
__device__ __forceinline__ int fragidx32(int n, int k) {
  return (((n >> 4) * 64 + ((k >> 3) & 3) * 16 + (n & 15)) << 3) + (k & 7);
}

// ---------------- weight pack (fp32 -> bf16 fragment tiles) ----------------
// ws (bf16 elems): W2f @0 (65536), W3f @65536 (65536), W4f @131072 (32768),
//   Wd-pad @163840 (4096: [256K][16N] col0=Wd), W5-pad @167936 (2048),
//   W1-pad @169984 (8192: [256N][32K], k0/1=W1r0, k2/3=W1r1, k4/5=W1r2, k6=b1)
__global__ void pack_weights(const float* __restrict__ W1, const float* __restrict__ b1,
                             const float* __restrict__ W2, const float* __restrict__ W3,
                             const float* __restrict__ W4, const float* __restrict__ Wd,
                             const float* __restrict__ W5, u16* __restrict__ ws) {
  int idx = blockIdx.x * 256 + threadIdx.x;   // grid covers exactly 178176
  float v;
  int dst;
  if (idx < 65536) {
    int k = idx >> 8, n = idx & 255;          // W2 row-major [k][n]
    v = W2[idx];
    dst = fragidx(n, k);
  } else if (idx < 131072) {
    int o = idx - 65536, k = o >> 8, n = o & 255;
    v = W3[o];
    dst = 65536 + fragidx(n, k);
  } else if (idx < 163840) {
    int o = idx - 131072, k = o >> 7, n = o & 127;  // W4 row-major [k][128]
    v = W4[o];
    dst = 131072 + fragidx(n, k);
  } else if (idx < 167936) {
    int o = idx - 163840, k = o >> 4, n = o & 15;   // Wd [256][1] padded to 16 cols
    v = (n == 0) ? Wd[k] : 0.f;
    dst = 163840 + fragidx(n, k);
  } else if (idx < 169984) {
    int o = idx - 167936, k = o >> 4, n = o & 15;   // W5 [128][3] padded to 16 cols
    v = (n < 3) ? W5[k * 3 + n] : 0.f;
    dst = 167936 + fragidx(n, k);
  } else {
    int o = idx - 169984, k = o >> 8, n = o & 255;  // W1-pad [256N][32K]
    if (k < 6)      v = W1[(k >> 1) * 256 + n];     // k0/1: row0; k2/3: row1; k4/5: row2
    else if (k == 6) v = b1[n];
    else            v = 0.f;
    dst = 169984 + fragidx32(n, k);
  }
  ws[dst] = f2bf(v);
}

#define MFMA __builtin_amdgcn_mfma_f32_16x16x32_bf16
#define ZER4 (f32x4){0.f, 0.f, 0.f, 0.f}

// declare + load the 4 A row-tile fragments for k-slice SQ from ACT
#define LDA4(ACT, SQ)                                                          \
    short8 av0 = *(const short8*)((ACT) + m0 * 256 + (((SQ) ^ (m0 & 31)) << 3)); \
    short8 av1 = *(const short8*)((ACT) + m1 * 256 + (((SQ) ^ (m1 & 31)) << 3)); \
    short8 av2 = *(const short8*)((ACT) + m2 * 256 + (((SQ) ^ (m2 & 31)) << 3)); \
    short8 av3 = *(const short8*)((ACT) + m3 * 256 + (((SQ) ^ (m3 & 31)) << 3))

// 16 MFMA: 4 row-tiles (av0..av3) x 4 B col-tiles (args)
#define MF16v(B0, B1, B2_, B3_) do {                                         \
    c00 = MFMA(av0, B0, c00, 0, 0, 0); c10 = MFMA(av1, B0, c10, 0, 0, 0);    \
    c20 = MFMA(av2, B0, c20, 0, 0, 0); c30 = MFMA(av3, B0, c30, 0, 0, 0);    \
    c01 = MFMA(av0, B1, c01, 0, 0, 0); c11 = MFMA(av1, B1, c11, 0, 0, 0);    \
    c21 = MFMA(av2, B1, c21, 0, 0, 0); c31 = MFMA(av3, B1, c31, 0, 0, 0);    \
    c02 = MFMA(av0, B2_, c02, 0, 0, 0); c12 = MFMA(av1, B2_, c12, 0, 0, 0);  \
    c22 = MFMA(av2, B2_, c22, 0, 0, 0); c32 = MFMA(av3, B2_, c32, 0, 0, 0);  \
    c03 = MFMA(av0, B3_, c03, 0, 0, 0); c13 = MFMA(av1, B3_, c13, 0, 0, 0);  \
    c23 = MFMA(av2, B3_, c23, 0, 0, 0); c33 = MFMA(av3, B3_, c33, 0, 0, 0);  \
  } while (0)

// store one 16x16 C-tile (f32x4 CV), row-tile mt, column ng, into swizzled ACT
#define EPIC(CV, mt, ng, addv, ACT) do {                                     \
    int su_ = ((ng) >> 3), so_ = ((ng) & 7);                                 \
    float f0_ = fmaxf((CV)[0] + (addv), 0.f);                                \
    float f1_ = fmaxf((CV)[1] + (addv), 0.f);                                \
    float f2_ = fmaxf((CV)[2] + (addv), 0.f);                                \
    float f3_ = fmaxf((CV)[3] + (addv), 0.f);                                \
    uint32_t p01_ = cvtpk(f0_, f1_), p23_ = cvtpk(f2_, f3_);                 \
    int mmb_ = (mt) * 16 + quad * 4;                                         \
    (ACT)[(mmb_ + 0) * 256 + ((su_ ^ ((mmb_ + 0) & 31)) << 3) + so_] = (u16)p01_;         \
    (ACT)[(mmb_ + 1) * 256 + ((su_ ^ ((mmb_ + 1) & 31)) << 3) + so_] = (u16)(p01_ >> 16); \
    (ACT)[(mmb_ + 2) * 256 + ((su_ ^ ((mmb_ + 2) & 31)) << 3) + so_] = (u16)p23_;         \
    (ACT)[(mmb_ + 3) * 256 + ((su_ ^ ((mmb_ + 3) & 31)) << 3) + so_] = (u16)(p23_ >> 16); \
  } while (0)

__global__ void __launch_bounds__(256, 2) nerf_fused(
    const float* __restrict__ rays_o, const float* __restrict__ rays_d,
    const float* __restrict__ t_rand,
    const float* __restrict__ b2, const float* __restrict__ b3,
    const float* __restrict__ bd,
    const float* __restrict__ W4, const float* __restrict__ b4,
    const float* __restrict__ b5,
    const u16* __restrict__ wpack, float* __restrict__ out) {
  __shared__ u16   actA[64 * 256];   // 32 KB, XOR-swizzled slots (ping)
  __shared__ u16   actB[64 * 256];   // 32 KB (pong)
  __shared__ float dens[64];
  __shared__ float rgbL[64 * 4];

  const int t = threadIdx.x;
  const int lane = t & 63;
  const int wv = t >> 6;        // 0..3
  const int quad = lane >> 4;
  const int l15 = lane & 15;
  const int ray = blockIdx.x;
  const int m0 = l15, m1 = l15 + 16, m2 = l15 + 32, m3 = l15 + 48;

  // ---- prefetch W1 frag (16 regs) + B2 kq0-3 (64 regs) ----
  short8 W1f0, W1f1, W1f2, W1f3;
  {
    const u16* w1b = wpack + 169984 + (wv * 4) * 512 + lane * 8;
    W1f0 = *(const short8*)(w1b);
    W1f1 = *(const short8*)(w1b + 512);
    W1f2 = *(const short8*)(w1b + 1024);
    W1f3 = *(const short8*)(w1b + 1536);
  }
  short8 B2a[8], B2b[8], B2c[8], B2d[8];
  const u16* q0 = wpack + (wv * 4 + 0) * 4096 + lane * 8;
  const u16* q1 = wpack + (wv * 4 + 1) * 4096 + lane * 8;
  const u16* q2 = wpack + (wv * 4 + 2) * 4096 + lane * 8;
  const u16* q3 = wpack + (wv * 4 + 3) * 4096 + lane * 8;
#pragma unroll
  for (int kq = 0; kq < 4; kq++) {
    B2a[kq] = *(const short8*)(q0 + kq * 512);
    B2b[kq] = *(const short8*)(q1 + kq * 512);
    B2c[kq] = *(const short8*)(q2 + kq * 512);
    B2d[kq] = *(const short8*)(q3 + kq * 512);
  }

  const float rox = rays_o[ray * 3 + 0], roy = rays_o[ray * 3 + 1], roz = rays_o[ray * 3 + 2];
  const float rdx = rays_d[ray * 3 + 0], rdy = rays_d[ray * 3 + 1], rdz = rays_d[ray * 3 + 2];

  // ---- layer 1 via MFMA: A built in regs (hi/lo split), no barrier before ----
  {
    short8 avz = {0, 0, 0, 0, 0, 0, 0, 0};
    short8 av0 = avz, av1 = avz, av2 = avz, av3 = avz;
    if (quad == 0) {
#pragma unroll
      for (int r = 0; r < 4; r++) {
        int m = l15 + r * 16;
        float tr = t_rand[ray * 64 + m];
        float zm = zval(m, tr);
        float px = rox + rdx * zm, py = roy + rdy * zm, pz = roz + rdz * zm;
        u16 xh = f2bf(px); float xl = px - bf2f(xh);
        u16 yh = f2bf(py); float yl = py - bf2f(yh);
        u16 zh = f2bf(pz); float zl = pz - bf2f(zh);
        short8 f;
        f[0] = (short)xh; f[1] = (short)f2bf(xl);
        f[2] = (short)yh; f[3] = (short)f2bf(yl);
        f[4] = (short)zh; f[5] = (short)f2bf(zl);
        f[6] = (short)0x3F80; f[7] = 0;
        if (r == 0) av0 = f; else if (r == 1) av1 = f;
        else if (r == 2) av2 = f; else av3 = f;
      }
    }
    f32x4 c00 = ZER4, c01 = ZER4, c02 = ZER4, c03 = ZER4;
    f32x4 c10 = ZER4, c11 = ZER4, c12 = ZER4, c13 = ZER4;
    f32x4 c20 = ZER4, c21 = ZER4, c22 = ZER4, c23 = ZER4;
    f32x4 c30 = ZER4, c31 = ZER4, c32 = ZER4, c33 = ZER4;
    MF16v(W1f0, W1f1, W1f2, W1f3);
    int ng0 = wv * 64 + l15;
    EPIC(c00, 0, ng0, 0.f, actA); EPIC(c10, 1, ng0, 0.f, actA);
    EPIC(c20, 2, ng0, 0.f, actA); EPIC(c30, 3, ng0, 0.f, actA);
    EPIC(c01, 0, ng0 + 16, 0.f, actA); EPIC(c11, 1, ng0 + 16, 0.f, actA);
    EPIC(c21, 2, ng0 + 16, 0.f, actA); EPIC(c31, 3, ng0 + 16, 0.f, actA);
    EPIC(c02, 0, ng0 + 32, 0.f, actA); EPIC(c12, 1, ng0 + 32, 0.f, actA);
    EPIC(c22, 2, ng0 + 32, 0.f, actA); EPIC(c32, 3, ng0 + 32, 0.f, actA);
    EPIC(c03, 0, ng0 + 48, 0.f, actA); EPIC(c13, 1, ng0 + 48, 0.f, actA);
    EPIC(c23, 2, ng0 + 48, 0.f, actA); EPIC(c33, 3, ng0 + 48, 0.f, actA);
  }
  // B2 kq4-7 AFTER L1 EPIC (acc dead): overlaps the barrier drain
#pragma unroll
  for (int kq = 4; kq < 8; kq++) {
    B2a[kq] = *(const short8*)(q0 + kq * 512);
    B2b[kq] = *(const short8*)(q1 + kq * 512);
    B2c[kq] = *(const short8*)(q2 + kq * 512);
    B2d[kq] = *(const short8*)(q3 + kq * 512);
  }
  __syncthreads();                                          // barrier 1 (of 4)

  short8 B3a[4], B3b[4], B3c[4], B3d[4];     // L3 kq0-3 prefetch (filled in L2)

  // ---- layer 2: h2 = relu(h1@W2 + b2) : reads actA, writes actB ----
  {
    int ng0 = wv * 64 + l15;
    float bi0 = b2[ng0], bi1 = b2[ng0 + 16], bi2 = b2[ng0 + 32], bi3 = b2[ng0 + 48];
    f32x4 c00 = ZER4, c01 = ZER4, c02 = ZER4, c03 = ZER4;
    f32x4 c10 = ZER4, c11 = ZER4, c12 = ZER4, c13 = ZER4;
    f32x4 c20 = ZER4, c21 = ZER4, c22 = ZER4, c23 = ZER4;
    f32x4 c30 = ZER4, c31 = ZER4, c32 = ZER4, c33 = ZER4;
#pragma unroll
    for (int kq = 0; kq < 8; kq++) {
      LDA4(actA, kq * 4 + quad);
      MF16v(B2a[kq], B2b[kq], B2c[kq], B2d[kq]);
    }
    // prefetch L3 B kq0-3 (R13's proven depth)
    {
      const u16* r0 = wpack + 65536 + (wv * 4 + 0) * 4096 + lane * 8;
      const u16* r1 = wpack + 65536 + (wv * 4 + 1) * 4096 + lane * 8;
      const u16* r2 = wpack + 65536 + (wv * 4 + 2) * 4096 + lane * 8;
      const u16* r3 = wpack + 65536 + (wv * 4 + 3) * 4096 + lane * 8;
#pragma unroll
      for (int kq = 0; kq < 4; kq++) {
        B3a[kq] = *(const short8*)(r0 + kq * 512);
        B3b[kq] = *(const short8*)(r1 + kq * 512);
        B3c[kq] = *(const short8*)(r2 + kq * 512);
        B3d[kq] = *(const short8*)(r3 + kq * 512);
      }
    }
    EPIC(c00, 0, ng0, bi0, actB); EPIC(c10, 1, ng0, bi0, actB);
    EPIC(c20, 2, ng0, bi0, actB); EPIC(c30, 3, ng0, bi0, actB);
    EPIC(c01, 0, ng0 + 16, bi1, actB); EPIC(c11, 1, ng0 + 16, bi1, actB);
    EPIC(c21, 2, ng0 + 16, bi1, actB); EPIC(c31, 3, ng0 + 16, bi1, actB);
    EPIC(c02, 0, ng0 + 32, bi2, actB); EPIC(c12, 1, ng0 + 32, bi2, actB);
    EPIC(c22, 2, ng0 + 32, bi2, actB); EPIC(c32, 3, ng0 + 32, bi2, actB);
    EPIC(c03, 0, ng0 + 48, bi3, actB); EPIC(c13, 1, ng0 + 48, bi3, actB);
    EPIC(c23, 2, ng0 + 48, bi3, actB); EPIC(c33, 3, ng0 + 48, bi3, actB);
  }
  __syncthreads();                                          // barrier 2

  short8 L4a[2], L4b[2], L4d[2];             // L4 kq0-1 prefetch (filled in L3)

  // ---- layer 3: h3 = relu(h2@W3 + b3) : reads actB, writes actA ----
  {
    int ng0 = wv * 64 + l15;
    float bi0 = b3[ng0], bi1 = b3[ng0 + 16], bi2 = b3[ng0 + 32], bi3 = b3[ng0 + 48];
    const u16* r0 = wpack + 65536 + (wv * 4 + 0) * 4096 + lane * 8;
    const u16* r1 = wpack + 65536 + (wv * 4 + 1) * 4096 + lane * 8;
    const u16* r2 = wpack + 65536 + (wv * 4 + 2) * 4096 + lane * 8;
    const u16* r3 = wpack + 65536 + (wv * 4 + 3) * 4096 + lane * 8;
    f32x4 c00 = ZER4, c01 = ZER4, c02 = ZER4, c03 = ZER4;
    f32x4 c10 = ZER4, c11 = ZER4, c12 = ZER4, c13 = ZER4;
    f32x4 c20 = ZER4, c21 = ZER4, c22 = ZER4, c23 = ZER4;
    f32x4 c30 = ZER4, c31 = ZER4, c32 = ZER4, c33 = ZER4;
#pragma unroll
    for (int kq = 0; kq < 8; kq++) {
      short8 b0, b1v, b2v, b3v;
      if (kq < 4) { b0 = B3a[kq]; b1v = B3b[kq]; b2v = B3c[kq]; b3v = B3d[kq]; }
      else {
        b0 = *(const short8*)(r0 + kq * 512);
        b1v = *(const short8*)(r1 + kq * 512);
        b2v = *(const short8*)(r2 + kq * 512);
        b3v = *(const short8*)(r3 + kq * 512);
      }
      LDA4(actB, kq * 4 + quad);
      MF16v(b0, b1v, b2v, b3v);
    }
    // prefetch L4 B kq0-1 + density-frag kq0-1
    {
      const u16* s0 = wpack + 131072 + (wv * 2 + 0) * 4096 + lane * 8;
      const u16* s1 = wpack + 131072 + (wv * 2 + 1) * 4096 + lane * 8;
      const u16* sD = wpack + 163840 + lane * 8;
#pragma unroll
      for (int kq = 0; kq < 2; kq++) {
        L4a[kq] = *(const short8*)(s0 + kq * 512);
        L4b[kq] = *(const short8*)(s1 + kq * 512);
        L4d[kq] = *(const short8*)(sD + kq * 512);
      }
    }
    EPIC(c00, 0, ng0, bi0, actA); EPIC(c10, 1, ng0, bi0, actA);
    EPIC(c20, 2, ng0, bi0, actA); EPIC(c30, 3, ng0, bi0, actA);
    EPIC(c01, 0, ng0 + 16, bi1, actA); EPIC(c11, 1, ng0 + 16, bi1, actA);
    EPIC(c21, 2, ng0 + 16, bi1, actA); EPIC(c31, 3, ng0 + 16, bi1, actA);
    EPIC(c02, 0, ng0 + 32, bi2, actA); EPIC(c12, 1, ng0 + 32, bi2, actA);
    EPIC(c22, 2, ng0 + 32, bi2, actA); EPIC(c32, 3, ng0 + 32, bi2, actA);
    EPIC(c03, 0, ng0 + 48, bi3, actA); EPIC(c13, 1, ng0 + 48, bi3, actA);
    EPIC(c23, 2, ng0 + 48, bi3, actA); EPIC(c33, 3, ng0 + 48, bi3, actA);
  }
  __syncthreads();                                          // barrier 3

  short8 W5f[4];                             // rgb B-frag prefetch (wave0 only)

  // ---- layer 4: h4 = relu(h3@W4 + vdir-term + b4), N=128; + fused density ----
  {
    float nrm = sqrtf(rdx * rdx + rdy * rdy + rdz * rdz) + 1e-8f;
    float v0 = rdx / nrm, v1 = rdy / nrm, v2 = rdz / nrm;
    int ng0 = wv * 32 + l15;
    int ng1 = ng0 + 16;
    float ad0 = b4[ng0] + v0 * W4[32768 + ng0] + v1 * W4[32896 + ng0] + v2 * W4[33024 + ng0];
    float ad1 = b4[ng1] + v0 * W4[32768 + ng1] + v1 * W4[32896 + ng1] + v2 * W4[33024 + ng1];
    const u16* s0 = wpack + 131072 + (wv * 2 + 0) * 4096 + lane * 8;
    const u16* s1 = wpack + 131072 + (wv * 2 + 1) * 4096 + lane * 8;
    const u16* sD = wpack + 163840 + lane * 8;
    f32x4 c00 = ZER4, c01 = ZER4;
    f32x4 c10 = ZER4, c11 = ZER4;
    f32x4 c20 = ZER4, c21 = ZER4;
    f32x4 c30 = ZER4, c31 = ZER4;
    f32x4 c40 = ZER4, c41 = ZER4, c42 = ZER4, c43 = ZER4;   // density
#pragma unroll
    for (int kq = 0; kq < 8; kq++) {
      short8 b0 = (kq < 2) ? L4a[kq] : *(const short8*)(s0 + kq * 512);
      short8 b1v = (kq < 2) ? L4b[kq] : *(const short8*)(s1 + kq * 512);
      short8 bD = (kq < 2) ? L4d[kq] : *(const short8*)(sD + kq * 512);
      LDA4(actA, kq * 4 + quad);
      c00 = MFMA(av0, b0, c00, 0, 0, 0); c10 = MFMA(av1, b0, c10, 0, 0, 0);
      c20 = MFMA(av2, b0, c20, 0, 0, 0); c30 = MFMA(av3, b0, c30, 0, 0, 0);
      c01 = MFMA(av0, b1v, c01, 0, 0, 0); c11 = MFMA(av1, b1v, c11, 0, 0, 0);
      c21 = MFMA(av2, b1v, c21, 0, 0, 0); c31 = MFMA(av3, b1v, c31, 0, 0, 0);
      c40 = MFMA(av0, bD, c40, 0, 0, 0); c41 = MFMA(av1, bD, c41, 0, 0, 0);
      c42 = MFMA(av2, bD, c42, 0, 0, 0); c43 = MFMA(av3, bD, c43, 0, 0, 0);
    }
    if (wv == 0) {       // only wave 0 needs W5 (it computes all rgb)
      const u16* s5 = wpack + 167936 + lane * 8;
#pragma unroll
      for (int kq = 0; kq < 4; kq++) W5f[kq] = *(const short8*)(s5 + kq * 512);
    }
    EPIC(c00, 0, ng0, ad0, actB); EPIC(c10, 1, ng0, ad0, actB);
    EPIC(c20, 2, ng0, ad0, actB); EPIC(c30, 3, ng0, ad0, actB);
    EPIC(c01, 0, ng1, ad1, actB); EPIC(c11, 1, ng1, ad1, actB);
    EPIC(c21, 2, ng1, ad1, actB); EPIC(c31, 3, ng1, ad1, actB);
    if (wv == 0 && l15 == 0) {
#pragma unroll
      for (int r = 0; r < 4; r++) {
        dens[ 0 + quad * 4 + r] = c40[r];
        dens[16 + quad * 4 + r] = c41[r];
        dens[32 + quad * 4 + r] = c42[r];
        dens[48 + quad * 4 + r] = c43[r];
      }
    }
  }
  __syncthreads();                                          // barrier 4 (last)

  // ---- wave 0: rgb (all rows via MFMA) + compositing; waves 1-3 exit ----
  if (wv == 0) {
    {
      f32x4 cR0 = ZER4, cR1 = ZER4, cR2 = ZER4, cR3 = ZER4;
#pragma unroll
      for (int kq = 0; kq < 4; kq++) {
        LDA4(actB, kq * 4 + quad);
        cR0 = MFMA(av0, W5f[kq], cR0, 0, 0, 0);
        cR1 = MFMA(av1, W5f[kq], cR1, 0, 0, 0);
        cR2 = MFMA(av2, W5f[kq], cR2, 0, 0, 0);
        cR3 = MFMA(av3, W5f[kq], cR3, 0, 0, 0);
      }
      if (l15 < 3) {
        float b5v = b5[l15];
#pragma unroll
        for (int r = 0; r < 4; r++) {
          rgbL[( 0 + quad * 4 + r) * 4 + l15] = 1.f / (1.f + __expf(-(cR0[r] + b5v)));
          rgbL[(16 + quad * 4 + r) * 4 + l15] = 1.f / (1.f + __expf(-(cR1[r] + b5v)));
          rgbL[(32 + quad * 4 + r) * 4 + l15] = 1.f / (1.f + __expf(-(cR2[r] + b5v)));
          rgbL[(48 + quad * 4 + r) * 4 + l15] = 1.f / (1.f + __expf(-(cR3[r] + b5v)));
        }
      }
    }
    // compositing (zv recomputed per lane, identical expression -> bit-identical)
    {
      int j = lane;
      float tr = t_rand[ray * 64 + j];
      float zvj = zval(j, tr);
      float zvn = __shfl_down(zvj, 1);
      float dist = (j < 63) ? (zvn - zvj) : 1e10f;
      float bd0 = bd[0];
      float alpha = 1.f - __expf(-fmaxf(dens[j] + bd0, 0.f) * dist);
      float v = 1.f - alpha + 1e-10f;
      float pscan = v;
#pragma unroll
      for (int d = 1; d < 64; d <<= 1) {
        float o = __shfl_up(pscan, d);
        if (j >= d) pscan *= o;
      }
      float T = __shfl_up(pscan, 1);
      if (j == 0) T = 1.f;
      float w = alpha * T;
      float r0 = w * rgbL[j * 4 + 0];
      float r1 = w * rgbL[j * 4 + 1];
      float r2 = w * rgbL[j * 4 + 2];
      float dp = w * zvj;
      float ac = w;
#pragma unroll
      for (int d = 32; d; d >>= 1) {
        r0 += __shfl_down(r0, d);
        r1 += __shfl_down(r1, d);
        r2 += __shfl_down(r2, d);
        dp += __shfl_down(dp, d);
        ac += __shfl_down(ac, d);
      }
      if (j == 0) {
        float bg = 1.f - ac;
        out[ray * 3 + 0] = r0 + bg;
        out[ray * 3 + 1] = r1 + bg;
        out[ray * 3 + 2] = r2 + bg;
        out[NRAYS * 3 + ray] = dp;
        out[NRAYS * 4 + ray] = ac;
      }
    }
  }
}

extern "C" void kernel_launch(void* const* d_in, const int* in_sizes, int n_in,
                              void* d_out, int out_size, void* d_ws, size_t ws_size,
                              hipStream_t stream) {
  const float* rays_o = (const float*)d_in[0];
  const float* rays_d = (const float*)d_in[1];
  const float* t_rand = (const float*)d_in[2];
  const float* W1 = (const float*)d_in[3];
  const float* b1 = (const float*)d_in[4];
  const float* W2 = (const float*)d_in[5];
  const float* b2 = (const float*)d_in[6];
  const float* W3 = (const float*)d_in[7];
  const float* b3 = (const float*)d_in[8];
  const float* Wd = (const float*)d_in[9];
  const float* bd = (const float*)d_in[10];
  const float* W4 = (const float*)d_in[11];
  const float* b4 = (const float*)d_in[12];
  const float* W5 = (const float*)d_in[13];
  const float* b5 = (const float*)d_in[14];
  u16* wpack = (u16*)d_ws;
  float* out = (float*)d_out;

  pack_weights<<<696, 256, 0, stream>>>(W1, b1, W2, W3, W4, Wd, W5, wpack);
  nerf_fused<<<NRAYS, 256, 0, stream>>>(rays_o, rays_d, t_rand, b2, b3,
                                        bd, W4, b4, b5, wpack, out);
}

// Round 10
// 220.484 us; speedup vs baseline: 1.6931x; 1.0555x over previous
//
#include <hip/hip_runtime.h>
#include <stdint.h>

// R16: R15 minus the full-B2 prefetch. R15 post-mortem: WRITE 184MB spill came
// from the L2 K-loop peak (B2 full 128 + acc 64 + A 16 + scalars ~220+); the
// ~210-edge is not safely predictable -> design all phases to peak <=~180.
// Change vs R15: B2 prefetch 4-deep rolling (kq0-3 in regs, kq4-7 loaded
// in-loop), the exact pattern proven spill-free in L3 since R13.
//   L1 peak ~150, L2 loop ~150, L3 ~150, L4 ~170. No phase near the edge.
// Tripwire: WRITE <=10MB (decisive). Predict kernel 140-152us, e2e ~205-215.
// If spill persists or >=160: revert to R13 verbatim next round.

#define NRAYS 4096

typedef unsigned short u16;
typedef __attribute__((ext_vector_type(8))) short short8;
typedef __attribute__((ext_vector_type(4))) float f32x4;

__device__ __forceinline__ u16 f2bf(float f) {
  union { float f; uint32_t i; } v; v.f = f;
  return (u16)((v.i + 0x7FFFu + ((v.i >> 16) & 1u)) >> 16);
}
__device__ __forceinline__ float bf2f(u16 u) {
  union { uint32_t i; float f; } v; v.i = ((uint32_t)u) << 16; return v.f;
}
// packed fp32->bf16 (RNE), lo -> bits 15:0, hi -> bits 31:16 (bit-identical to f2bf)
__device__ __forceinline__ uint32_t cvtpk(float lo, float hi) {
  uint32_t r;
  asm("v_cvt_pk_bf16_f32 %0, %1, %2" : "=v"(r) : "v"(lo), "v"(hi));
  return r;
}

// stratified z sample for slot j (MUST stay textually identical everywhere)
__device__ __forceinline__ float zval(int j, float tr) {
  float fj = (float)j;
  float zj = 0.5f + 2.0f * (fj / 63.0f);
  float lower = (j == 0)  ? zj : 0.5f * (zj + (0.5f + 2.0f * ((fj - 1.0f) / 63.0f)));
  float upper = (j == 63) ? zj : 0.5f * (zj + (0.5f + 2.0f * ((fj + 1.0f) / 63.0f)));
  return lower + (upper - lower) * tr;
}

// fragment-contiguous index for a [N][K=256] tile (8 kq blocks)
__device__ __forceinline__ int fragidx(int n, int k) {
  return ((((n >> 4) * 8 + (k >> 5)) * 64 + ((k >> 3) & 3) * 16 + (n & 15)) << 3) + (k & 7);
}
// same for a [N][K=32] tile (1 kq block)
__device__ __forceinline__ int fragidx32(int n, int k) {
  return (((n >> 4) * 64 + ((k >> 3) & 3) * 16 + (n & 15)) << 3) + (k & 7);
}

// ---------------- weight pack (fp32 -> bf16 fragment tiles) ----------------
// ws (bf16 elems): W2f @0 (65536), W3f @65536 (65536), W4f @131072 (32768),
//   Wd-pad @163840 (4096: [256K][16N] col0=Wd), W5-pad @167936 (2048),
//   W1-pad @169984 (8192: [256N][32K], k0/1=W1r0, k2/3=W1r1, k4/5=W1r2, k6=b1)
__global__ void pack_weights(const float* __restrict__ W1, const float* __restrict__ b1,
                             const float* __restrict__ W2, const float* __restrict__ W3,
                             const float* __restrict__ W4, const float* __restrict__ Wd,
                             const float* __restrict__ W5, u16* __restrict__ ws) {
  int idx = blockIdx.x * 256 + threadIdx.x;   // grid covers exactly 178176
  float v;
  int dst;
  if (idx < 65536) {
    int k = idx >> 8, n = idx & 255;          // W2 row-major [k][n]
    v = W2[idx];
    dst = fragidx(n, k);
  } else if (idx < 131072) {
    int o = idx - 65536, k = o >> 8, n = o & 255;
    v = W3[o];
    dst = 65536 + fragidx(n, k);
  } else if (idx < 163840) {
    int o = idx - 131072, k = o >> 7, n = o & 127;  // W4 row-major [k][128]
    v = W4[o];
    dst = 131072 + fragidx(n, k);
  } else if (idx < 167936) {
    int o = idx - 163840, k = o >> 4, n = o & 15;   // Wd [256][1] padded to 16 cols
    v = (n == 0) ? Wd[k] : 0.f;
    dst = 163840 + fragidx(n, k);
  } else if (idx < 169984) {
    int o = idx - 167936, k = o >> 4, n = o & 15;   // W5 [128][3] padded to 16 cols
    v = (n < 3) ? W5[k * 3 + n] : 0.f;
    dst = 167936 + fragidx(n, k);
  } else {
    int o = idx - 169984, k = o >> 8, n = o & 255;  // W1-pad [256N][32K]
    if (k < 6)      v = W1[(k >> 1) * 256 + n];     // k0/1: row0; k2/3: row1; k4/5: row2
    else if (k == 6) v = b1[n];
    else            v = 0.f;
    dst = 169984 + fragidx32(n, k);
  }
  ws[dst] = f2bf(v);
}

#define MFMA __builtin_amdgcn_mfma_f32_16x16x32_bf16
#define ZER4 (f32x4){0.f, 0.f, 0.f, 0.f}

// declare + load the 4 A row-tile fragments for k-slice SQ from ACT
#define LDA4(ACT, SQ)                                                          \
    short8 av0 = *(const short8*)((ACT) + m0 * 256 + (((SQ) ^ (m0 & 31)) << 3)); \
    short8 av1 = *(const short8*)((ACT) + m1 * 256 + (((SQ) ^ (m1 & 31)) << 3)); \
    short8 av2 = *(const short8*)((ACT) + m2 * 256 + (((SQ) ^ (m2 & 31)) << 3)); \
    short8 av3 = *(const short8*)((ACT) + m3 * 256 + (((SQ) ^ (m3 & 31)) << 3))

// 16 MFMA: 4 row-tiles (av0..av3) x 4 B col-tiles (args)
#define MF16v(B0, B1, B2_, B3_) do {                                         \
    c00 = MFMA(av0, B0, c00, 0, 0, 0); c10 = MFMA(av1, B0, c10, 0, 0, 0);    \
    c20 = MFMA(av2, B0, c20, 0, 0, 0); c30 = MFMA(av3, B0, c30, 0, 0, 0);    \
    c01 = MFMA(av0, B1, c01, 0, 0, 0); c11 = MFMA(av1, B1, c11, 0, 0, 0);    \
    c21 = MFMA(av2, B1, c21, 0, 0, 0); c31 = MFMA(av3, B1, c31, 0, 0, 0);    \
    c02 = MFMA(av0, B2_, c02, 0, 0, 0); c12 = MFMA(av1, B2_, c12, 0, 0, 0);  \
    c22 = MFMA(av2, B2_, c22, 0, 0, 0); c32 = MFMA(av3, B2_, c32, 0, 0, 0);  \
    c03 = MFMA(av0, B3_, c03, 0, 0, 0); c13 = MFMA(av1, B3_, c13, 0, 0, 0);  \
    c23 = MFMA(av2, B3_, c23, 0, 0, 0); c33 = MFMA(av3, B3_, c33, 0, 0, 0);  \
  } while (0)

// store one 16x16 C-tile (f32x4 CV), row-tile mt, column ng, into swizzled ACT
#define EPIC(CV, mt, ng, addv, ACT) do {                                     \
    int su_ = ((ng) >> 3), so_ = ((ng) & 7);                                 \
    float f0_ = fmaxf((CV)[0] + (addv), 0.f);                                \
    float f1_ = fmaxf((CV)[1] + (addv), 0.f);                                \
    float f2_ = fmaxf((CV)[2] + (addv), 0.f);                                \
    float f3_ = fmaxf((CV)[3] + (addv), 0.f);                                \
    uint32_t p01_ = cvtpk(f0_, f1_), p23_ = cvtpk(f2_, f3_);                 \
    int mmb_ = (mt) * 16 + quad * 4;                                         \
    (ACT)[(mmb_ + 0) * 256 + ((su_ ^ ((mmb_ + 0) & 31)) << 3) + so_] = (u16)p01_;         \
    (ACT)[(mmb_ + 1) * 256 + ((su_ ^ ((mmb_ + 1) & 31)) << 3) + so_] = (u16)(p01_ >> 16); \
    (ACT)[(mmb_ + 2) * 256 + ((su_ ^ ((mmb_ + 2) & 31)) << 3) + so_] = (u16)p23_;         \
    (ACT)[(mmb_ + 3) * 256 + ((su_ ^ ((mmb_ + 3) & 31)) << 3) + so_] = (u16)(p23_ >> 16); \
  } while (0)

__global__ void __launch_bounds__(256, 2) nerf_fused(
    const float* __restrict__ rays_o, const float* __restrict__ rays_d,
    const float* __restrict__ t_rand,
    const float* __restrict__ b2, const float* __restrict__ b3,
    const float* __restrict__ bd,
    const float* __restrict__ W4, const float* __restrict__ b4,
    const float* __restrict__ b5,
    const u16* __restrict__ wpack, float* __restrict__ out) {
  __shared__ u16   actA[64 * 256];   // 32 KB, XOR-swizzled slots (ping)
  __shared__ u16   actB[64 * 256];   // 32 KB (pong)
  __shared__ float dens[64];
  __shared__ float rgbL[64 * 4];

  const int t = threadIdx.x;
  const int lane = t & 63;
  const int wv = t >> 6;        // 0..3
  const int quad = lane >> 4;
  const int l15 = lane & 15;
  const int ray = blockIdx.x;
  const int m0 = l15, m1 = l15 + 16, m2 = l15 + 32, m3 = l15 + 48;

  // ---- prefetch W1 frag (16 regs) + B2 kq0-3 (64 regs) ----
  short8 W1f0, W1f1, W1f2, W1f3;
  {
    const u16* w1b = wpack + 169984 + (wv * 4) * 512 + lane * 8;
    W1f0 = *(const short8*)(w1b);
    W1f1 = *(const short8*)(w1b + 512);
    W1f2 = *(const short8*)(w1b + 1024);
    W1f3 = *(const short8*)(w1b + 1536);
  }
  short8 B2a[4], B2b[4], B2c[4], B2d[4];
  const u16* q0 = wpack + (wv * 4 + 0) * 4096 + lane * 8;
  const u16* q1 = wpack + (wv * 4 + 1) * 4096 + lane * 8;
  const u16* q2 = wpack + (wv * 4 + 2) * 4096 + lane * 8;
  const u16* q3 = wpack + (wv * 4 + 3) * 4096 + lane * 8;
#pragma unroll
  for (int kq = 0; kq < 4; kq++) {
    B2a[kq] = *(const short8*)(q0 + kq * 512);
    B2b[kq] = *(const short8*)(q1 + kq * 512);
    B2c[kq] = *(const short8*)(q2 + kq * 512);
    B2d[kq] = *(const short8*)(q3 + kq * 512);
  }

  const float rox = rays_o[ray * 3 + 0], roy = rays_o[ray * 3 + 1], roz = rays_o[ray * 3 + 2];
  const float rdx = rays_d[ray * 3 + 0], rdy = rays_d[ray * 3 + 1], rdz = rays_d[ray * 3 + 2];

  // ---- layer 1 via MFMA: A built in regs (hi/lo split), no barrier before ----
  {
    short8 avz = {0, 0, 0, 0, 0, 0, 0, 0};
    short8 av0 = avz, av1 = avz, av2 = avz, av3 = avz;
    if (quad == 0) {
#pragma unroll
      for (int r = 0; r < 4; r++) {
        int m = l15 + r * 16;
        float tr = t_rand[ray * 64 + m];
        float zm = zval(m, tr);
        float px = rox + rdx * zm, py = roy + rdy * zm, pz = roz + rdz * zm;
        u16 xh = f2bf(px); float xl = px - bf2f(xh);
        u16 yh = f2bf(py); float yl = py - bf2f(yh);
        u16 zh = f2bf(pz); float zl = pz - bf2f(zh);
        short8 f;
        f[0] = (short)xh; f[1] = (short)f2bf(xl);
        f[2] = (short)yh; f[3] = (short)f2bf(yl);
        f[4] = (short)zh; f[5] = (short)f2bf(zl);
        f[6] = (short)0x3F80; f[7] = 0;
        if (r == 0) av0 = f; else if (r == 1) av1 = f;
        else if (r == 2) av2 = f; else av3 = f;
      }
    }
    f32x4 c00 = ZER4, c01 = ZER4, c02 = ZER4, c03 = ZER4;
    f32x4 c10 = ZER4, c11 = ZER4, c12 = ZER4, c13 = ZER4;
    f32x4 c20 = ZER4, c21 = ZER4, c22 = ZER4, c23 = ZER4;
    f32x4 c30 = ZER4, c31 = ZER4, c32 = ZER4, c33 = ZER4;
    MF16v(W1f0, W1f1, W1f2, W1f3);
    int ng0 = wv * 64 + l15;
    EPIC(c00, 0, ng0, 0.f, actA); EPIC(c10, 1, ng0, 0.f, actA);
    EPIC(c20, 2, ng0, 0.f, actA); EPIC(c30, 3, ng0, 0.f, actA);
    EPIC(c01, 0, ng0 + 16, 0.f, actA); EPIC(c11, 1, ng0 + 16, 0.f, actA);
    EPIC(c21, 2, ng0 + 16, 0.f, actA); EPIC(c31, 3, ng0 + 16, 0.f, actA);
    EPIC(c02, 0, ng0 + 32, 0.f, actA); EPIC(c12, 1, ng0 + 32, 0.f, actA);
    EPIC(c22, 2, ng0 + 32, 0.f, actA); EPIC(c32, 3, ng0 + 32, 0.f, actA);
    EPIC(c03, 0, ng0 + 48, 0.f, actA); EPIC(c13, 1, ng0 + 48, 0.f, actA);
    EPIC(c23, 2, ng0 + 48, 0.f, actA); EPIC(c33, 3, ng0 + 48, 0.f, actA);
  }
  __syncthreads();                                          // barrier 1 (of 4)

  short8 B3a[4], B3b[4], B3c[4], B3d[4];     // L3 kq0-3 prefetch (filled in L2)

  // ---- layer 2: h2 = relu(h1@W2 + b2) : reads actA, writes actB ----
  // B2 kq0-3 from prefetch regs; kq4-7 loaded in-loop (L3's proven pattern)
  {
    int ng0 = wv * 64 + l15;
    float bi0 = b2[ng0], bi1 = b2[ng0 + 16], bi2 = b2[ng0 + 32], bi3 = b2[ng0 + 48];
    f32x4 c00 = ZER4, c01 = ZER4, c02 = ZER4, c03 = ZER4;
    f32x4 c10 = ZER4, c11 = ZER4, c12 = ZER4, c13 = ZER4;
    f32x4 c20 = ZER4, c21 = ZER4, c22 = ZER4, c23 = ZER4;
    f32x4 c30 = ZER4, c31 = ZER4, c32 = ZER4, c33 = ZER4;
#pragma unroll
    for (int kq = 0; kq < 8; kq++) {
      short8 b0, b1v, b2v, b3v;
      if (kq < 4) { b0 = B2a[kq]; b1v = B2b[kq]; b2v = B2c[kq]; b3v = B2d[kq]; }
      else {
        b0 = *(const short8*)(q0 + kq * 512);
        b1v = *(const short8*)(q1 + kq * 512);
        b2v = *(const short8*)(q2 + kq * 512);
        b3v = *(const short8*)(q3 + kq * 512);
      }
      LDA4(actA, kq * 4 + quad);
      MF16v(b0, b1v, b2v, b3v);
    }
    // prefetch L3 B kq0-3
    {
      const u16* r0 = wpack + 65536 + (wv * 4 + 0) * 4096 + lane * 8;
      const u16* r1 = wpack + 65536 + (wv * 4 + 1) * 4096 + lane * 8;
      const u16* r2 = wpack + 65536 + (wv * 4 + 2) * 4096 + lane * 8;
      const u16* r3 = wpack + 65536 + (wv * 4 + 3) * 4096 + lane * 8;
#pragma unroll
      for (int kq = 0; kq < 4; kq++) {
        B3a[kq] = *(const short8*)(r0 + kq * 512);
        B3b[kq] = *(const short8*)(r1 + kq * 512);
        B3c[kq] = *(const short8*)(r2 + kq * 512);
        B3d[kq] = *(const short8*)(r3 + kq * 512);
      }
    }
    EPIC(c00, 0, ng0, bi0, actB); EPIC(c10, 1, ng0, bi0, actB);
    EPIC(c20, 2, ng0, bi0, actB); EPIC(c30, 3, ng0, bi0, actB);
    EPIC(c01, 0, ng0 + 16, bi1, actB); EPIC(c11, 1, ng0 + 16, bi1, actB);
    EPIC(c21, 2, ng0 + 16, bi1, actB); EPIC(c31, 3, ng0 + 16, bi1, actB);
    EPIC(c02, 0, ng0 + 32, bi2, actB); EPIC(c12, 1, ng0 + 32, bi2, actB);
    EPIC(c22, 2, ng0 + 32, bi2, actB); EPIC(c32, 3, ng0 + 32, bi2, actB);
    EPIC(c03, 0, ng0 + 48, bi3, actB); EPIC(c13, 1, ng0 + 48, bi3, actB);
    EPIC(c23, 2, ng0 + 48, bi3, actB); EPIC(c33, 3, ng0 + 48, bi3, actB);
  }
  __syncthreads();                                          // barrier 2

  short8 L4a[2], L4b[2], L4d[2];             // L4 kq0-1 prefetch (filled in L3)

  // ---- layer 3: h3 = relu(h2@W3 + b3) : reads actB, writes actA ----
  {
    int ng0 = wv * 64 + l15;
    float bi0 = b3[ng0], bi1 = b3[ng0 + 16], bi2 = b3[ng0 + 32], bi3 = b3[ng0 + 48];
    const u16* r0 = wpack + 65536 + (wv * 4 + 0) * 4096 + lane * 8;
    const u16* r1 = wpack + 65536 + (wv * 4 + 1) * 4096 + lane * 8;
    const u16* r2 = wpack + 65536 + (wv * 4 + 2) * 4096 + lane * 8;
    const u16* r3 = wpack + 65536 + (wv * 4 + 3) * 4096 + lane * 8;
    f32x4 c00 = ZER4, c01 = ZER4, c02 = ZER4, c03 = ZER4;
    f32x4 c10 = ZER4, c11 = ZER4, c12 = ZER4, c13 = ZER4;
    f32x4 c20 = ZER4, c21 = ZER4, c22 = ZER4, c23 = ZER4;
    f32x4 c30 = ZER4, c31 = ZER4, c32 = ZER4, c33 = ZER4;
#pragma unroll
    for (int kq = 0; kq < 8; kq++) {
      short8 b0, b1v, b2v, b3v;
      if (kq < 4) { b0 = B3a[kq]; b1v = B3b[kq]; b2v = B3c[kq]; b3v = B3d[kq]; }
      else {
        b0 = *(const short8*)(r0 + kq * 512);
        b1v = *(const short8*)(r1 + kq * 512);
        b2v = *(const short8*)(r2 + kq * 512);
        b3v = *(const short8*)(r3 + kq * 512);
      }
      LDA4(actB, kq * 4 + quad);
      MF16v(b0, b1v, b2v, b3v);
    }
    // prefetch L4 B kq0-1 + density-frag kq0-1
    {
      const u16* s0 = wpack + 131072 + (wv * 2 + 0) * 4096 + lane * 8;
      const u16* s1 = wpack + 131072 + (wv * 2 + 1) * 4096 + lane * 8;
      const u16* sD = wpack + 163840 + lane * 8;
#pragma unroll
      for (int kq = 0; kq < 2; kq++) {
        L4a[kq] = *(const short8*)(s0 + kq * 512);
        L4b[kq] = *(const short8*)(s1 + kq * 512);
        L4d[kq] = *(const short8*)(sD + kq * 512);
      }
    }
    EPIC(c00, 0, ng0, bi0, actA); EPIC(c10, 1, ng0, bi0, actA);
    EPIC(c20, 2, ng0, bi0, actA); EPIC(c30, 3, ng0, bi0, actA);
    EPIC(c01, 0, ng0 + 16, bi1, actA); EPIC(c11, 1, ng0 + 16, bi1, actA);
    EPIC(c21, 2, ng0 + 16, bi1, actA); EPIC(c31, 3, ng0 + 16, bi1, actA);
    EPIC(c02, 0, ng0 + 32, bi2, actA); EPIC(c12, 1, ng0 + 32, bi2, actA);
    EPIC(c22, 2, ng0 + 32, bi2, actA); EPIC(c32, 3, ng0 + 32, bi2, actA);
    EPIC(c03, 0, ng0 + 48, bi3, actA); EPIC(c13, 1, ng0 + 48, bi3, actA);
    EPIC(c23, 2, ng0 + 48, bi3, actA); EPIC(c33, 3, ng0 + 48, bi3, actA);
  }
  __syncthreads();                                          // barrier 3

  short8 W5f[4];                             // rgb B-frag prefetch (wave0 only)

  // ---- layer 4: h4 = relu(h3@W4 + vdir-term + b4), N=128; + fused density ----
  {
    float nrm = sqrtf(rdx * rdx + rdy * rdy + rdz * rdz) + 1e-8f;
    float v0 = rdx / nrm, v1 = rdy / nrm, v2 = rdz / nrm;
    int ng0 = wv * 32 + l15;
    int ng1 = ng0 + 16;
    float ad0 = b4[ng0] + v0 * W4[32768 + ng0] + v1 * W4[32896 + ng0] + v2 * W4[33024 + ng0];
    float ad1 = b4[ng1] + v0 * W4[32768 + ng1] + v1 * W4[32896 + ng1] + v2 * W4[33024 + ng1];
    const u16* s0 = wpack + 131072 + (wv * 2 + 0) * 4096 + lane * 8;
    const u16* s1 = wpack + 131072 + (wv * 2 + 1) * 4096 + lane * 8;
    const u16* sD = wpack + 163840 + lane * 8;
    f32x4 c00 = ZER4, c01 = ZER4;
    f32x4 c10 = ZER4, c11 = ZER4;
    f32x4 c20 = ZER4, c21 = ZER4;
    f32x4 c30 = ZER4, c31 = ZER4;
    f32x4 c40 = ZER4, c41 = ZER4, c42 = ZER4, c43 = ZER4;   // density
#pragma unroll
    for (int kq = 0; kq < 8; kq++) {
      short8 b0 = (kq < 2) ? L4a[kq] : *(const short8*)(s0 + kq * 512);
      short8 b1v = (kq < 2) ? L4b[kq] : *(const short8*)(s1 + kq * 512);
      short8 bD = (kq < 2) ? L4d[kq] : *(const short8*)(sD + kq * 512);
      LDA4(actA, kq * 4 + quad);
      c00 = MFMA(av0, b0, c00, 0, 0, 0); c10 = MFMA(av1, b0, c10, 0, 0, 0);
      c20 = MFMA(av2, b0, c20, 0, 0, 0); c30 = MFMA(av3, b0, c30, 0, 0, 0);
      c01 = MFMA(av0, b1v, c01, 0, 0, 0); c11 = MFMA(av1, b1v, c11, 0, 0, 0);
      c21 = MFMA(av2, b1v, c21, 0, 0, 0); c31 = MFMA(av3, b1v, c31, 0, 0, 0);
      c40 = MFMA(av0, bD, c40, 0, 0, 0); c41 = MFMA(av1, bD, c41, 0, 0, 0);
      c42 = MFMA(av2, bD, c42, 0, 0, 0); c43 = MFMA(av3, bD, c43, 0, 0, 0);
    }
    if (wv == 0) {       // only wave 0 needs W5 (it computes all rgb)
      const u16* s5 = wpack + 167936 + lane * 8;
#pragma unroll
      for (int kq = 0; kq < 4; kq++) W5f[kq] = *(const short8*)(s5 + kq * 512);
    }
    EPIC(c00, 0, ng0, ad0, actB); EPIC(c10, 1, ng0, ad0, actB);
    EPIC(c20, 2, ng0, ad0, actB); EPIC(c30, 3, ng0, ad0, actB);
    EPIC(c01, 0, ng1, ad1, actB); EPIC(c11, 1, ng1, ad1, actB);
    EPIC(c21, 2, ng1, ad1, actB); EPIC(c31, 3, ng1, ad1, actB);
    if (wv == 0 && l15 == 0) {
#pragma unroll
      for (int r = 0; r < 4; r++) {
        dens[ 0 + quad * 4 + r] = c40[r];
        dens[16 + quad * 4 + r] = c41[r];
        dens[32 + quad * 4 + r] = c42[r];
        dens[48 + quad * 4 + r] = c43[r];
      }
    }
  }
  __syncthreads();                                          // barrier 4 (last)

  // ---- wave 0: rgb (all rows via MFMA) + compositing; waves 1-3 exit ----
  if (wv == 0) {
    {
      f32x4 cR0 = ZER4, cR1 = ZER4, cR2 = ZER4, cR3 = ZER4;
#pragma unroll
      for (int kq = 0; kq < 4; kq++) {
        LDA4(actB, kq * 4 + quad);
        cR0 = MFMA(av0, W5f[kq], cR0, 0, 0, 0);
        cR1 = MFMA(av1, W5f[kq], cR1, 0, 0, 0);
        cR2 = MFMA(av2, W5f[kq], cR2, 0, 0, 0);
        cR3 = MFMA(av3, W5f[kq], cR3, 0, 0, 0);
      }
      if (l15 < 3) {
        float b5v = b5[l15];
#pragma unroll
        for (int r = 0; r < 4; r++) {
          rgbL[( 0 + quad * 4 + r) * 4 + l15] = 1.f / (1.f + __expf(-(cR0[r] + b5v)));
          rgbL[(16 + quad * 4 + r) * 4 + l15] = 1.f / (1.f + __expf(-(cR1[r] + b5v)));
          rgbL[(32 + quad * 4 + r) * 4 + l15] = 1.f / (1.f + __expf(-(cR2[r] + b5v)));
          rgbL[(48 + quad * 4 + r) * 4 + l15] = 1.f / (1.f + __expf(-(cR3[r] + b5v)));
        }
      }
    }
    // compositing (zv recomputed per lane, identical expression -> bit-identical)
    {
      int j = lane;
      float tr = t_rand[ray * 64 + j];
      float zvj = zval(j, tr);
      float zvn = __shfl_down(zvj, 1);
      float dist = (j < 63) ? (zvn - zvj) : 1e10f;
      float bd0 = bd[0];
      float alpha = 1.f - __expf(-fmaxf(dens[j] + bd0, 0.f) * dist);
      float v = 1.f - alpha + 1e-10f;
      float pscan = v;
#pragma unroll
      for (int d = 1; d < 64; d <<= 1) {
        float o = __shfl_up(pscan, d);
        if (j >= d) pscan *= o;
      }
      float T = __shfl_up(pscan, 1);
      if (j == 0) T = 1.f;
      float w = alpha * T;
      float r0 = w * rgbL[j * 4 + 0];
      float r1 = w * rgbL[j * 4 + 1];
      float r2 = w * rgbL[j * 4 + 2];
      float dp = w * zvj;
      float ac = w;
#pragma unroll
      for (int d = 32; d; d >>= 1) {
        r0 += __shfl_down(r0, d);
        r1 += __shfl_down(r1, d);
        r2 += __shfl_down(r2, d);
        dp += __shfl_down(dp, d);
        ac += __shfl_down(ac, d);
      }
      if (j == 0) {
        float bg = 1.f - ac;
        out[ray * 3 + 0] = r0 + bg;
        out[ray * 3 + 1] = r1 + bg;
        out[ray * 3 + 2] = r2 + bg;
        out[NRAYS * 3 + ray] = dp;
        out[NRAYS * 4 + ray] = ac;
      }
    }
  }
}

extern "C" void kernel_launch(void* const* d_in, const int* in_sizes, int n_in,
                              void* d_out, int out_size, void* d_ws, size_t ws_size,
                              hipStream_t stream) {
  const float* rays_o = (const float*)d_in[0];
  const float* rays_d = (const float*)d_in[1];
  const float* t_rand = (const float*)d_in[2];
  const float* W1 = (const float*)d_in[3];
  const float* b1 = (const float*)d_in[4];
  const float* W2 = (const float*)d_in[5];
  const float* b2 = (const float*)d_in[6];
  const float* W3 = (const float*)d_in[7];
  const float* b3 = (const float*)d_in[8];
  const float* Wd = (const float*)d_in[9];
  const float* bd = (const float*)d_in[10];
  const float* W4 = (const float*)d_in[11];
  const float* b4 = (const float*)d_in[12];
  const float* W5 = (const float*)d_in[13];
  const float* b5 = (const float*)d_in[14];
  u16* wpack = (u16*)d_ws;
  float* out = (float*)d_out;

  pack_weights<<<696, 256, 0, stream>>>(W1, b1, W2, W3, W4, Wd, W5, wpack);
  nerf_fused<<<NRAYS, 256, 0, stream>>>(rays_o, rays_d, t_rand, b2, b3,
                                        bd, W4, b4, b5, wpack, out);
}